// Round 5
// baseline (16979.890 us; speedup 1.0000x reference)
//
#include <hip/hip_runtime.h>

// MLPDecoder_Causal: B=8,N=32,T=32,D=4,K=2,H=256,P=4,E=992.
// R5: same simple VALU kernel as R4, but ALL OUTPUTS WRITTEN AS FP32
// (R4 post-mortem: finite error ~1.5x max|ref| == bf16-written-into-fp32-buffer
// signature; reference declares fp32 outputs). Input dtype still auto-detected.
// ws use: 64KB (fp32 `last` ping-pong only).
typedef unsigned short u16;
typedef unsigned int   u32;
typedef unsigned long long u64;

__device__ __forceinline__ float bf2f(u16 s){ u32 u = ((u32)s)<<16; float f; __builtin_memcpy(&f,&u,4); return f; }
// generic input accessor: F=1 -> memory is bf16 (u16), F=0 -> fp32
__device__ __forceinline__ float inV(const void* p, int i, int F){
  return F ? bf2f(((const u16*)p)[i]) : ((const float*)p)[i];
}

// wave0 scans first 512 u16 of `inputs`: bf16 N(0,1) data never has exponent
// field >= 0xA0 (|x|>=2^33); fp32 low-halves hit that ~37% of the time.
__device__ __forceinline__ void detect_bf16(const void* inputs0, int tid, int* flagL){
  if (tid < 64){
    const uint4* dp = (const uint4*)inputs0;
    uint4 v = dp[tid];
    u32 wds[4] = {v.x, v.y, v.z, v.w};
    int sus = 0;
#pragma unroll
    for (int i2=0; i2<4; ++i2){
      u32 wv = wds[i2];
      u32 h0 = wv & 0xffffu, h1 = wv >> 16;
      if (((h0>>7)&0xffu) >= 0xA0u) sus = 1;
      if (((h1>>7)&0xffu) >= 0xA0u) sus = 1;
    }
    u64 bal = __ballot(sus);
    if (tid == 0) *flagL = (bal == 0ull) ? 1 : 0;
  }
}

#define WS_LAST0  0
#define WS_LAST1  32768

// ---------------- prep: last0 init + rel_out broadcast ----------------
__global__ void k_prep(const void* __restrict__ inputs, const void* __restrict__ rel_graph,
                       float* __restrict__ last0, float* __restrict__ out)
{
  __shared__ int flagL;
  int tid = threadIdx.x;
  detect_bf16(inputs, tid, &flagL);
  __syncthreads();
  const int F = flagL;
  int i = blockIdx.x*256 + tid;
  if (i < 8192){               // last0[bt][n][d] = inputs[b, n, 4*tp, d]
    int d = i&3, n = (i>>2)&31, bt = i>>7;
    int b = bt>>3, tp = bt&7;
    last0[i] = inV(inputs, b*4096 + n*128 + tp*16 + d, F);
    return;
  }
  i -= 8192;
  if (i < 15872) out[31744 + i] = inV(rel_graph, i % 1984, F);
}

// ---------------- per-step kernel: block = (bt, receiver n) ----------------
// 256 threads: thread (rg=tid>>5, cg=tid&31) owns rows j in {rg,rg+8,rg+16,rg+24}
// (j==31 is a pad row, masked) and cols c = cg*8..cg*8+7.
__global__ __launch_bounds__(256) void k_step(
    const void* __restrict__ inputs,
    const float* __restrict__ lastIn, float* __restrict__ lastOut,
    const void* __restrict__ rgg, const void* __restrict__ gbg,
    const void* __restrict__ W1, const void* __restrict__ b1,
    const void* __restrict__ W2, const void* __restrict__ b2,
    const void* __restrict__ Wo1, const void* __restrict__ bo1,
    const void* __restrict__ Wo2, const void* __restrict__ bo2,
    const void* __restrict__ Wo3, const void* __restrict__ bo3,
    float* __restrict__ hooks, float* __restrict__ out0, int pstep)
{
  __shared__ int   flagL;
  __shared__ float xj[32][8];      // [send(4) | recv(4)]; row 31 = zero pad
  __shared__ float evL[31][2];
  __shared__ float aggL[256];
  __shared__ float h1all[32][256];
  __shared__ float augS[260];
  __shared__ float o1L[256];
  __shared__ float o2L[256];

  const int tid = threadIdx.x;
  const int n = blockIdx.x & 31, bt = blockIdx.x >> 5;
  const int b = bt>>3, tp = bt&7;
  const int cg = tid & 31, rg = tid >> 5;

  detect_bf16(inputs, tid, &flagL);
  if (tid >= 64 && tid < 96){      // xj staging from fp32 ws (no dtype issue)
    int j = tid - 64;
    if (j < 31){
      int s = j + (j >= n);
#pragma unroll
      for (int d=0; d<4; ++d){
        xj[j][d]   = lastIn[bt*128 + s*4 + d];
        xj[j][4+d] = lastIn[bt*128 + n*4 + d];
      }
    } else {
#pragma unroll
      for (int d=0; d<8; ++d) xj[31][d] = 0.f;
    }
  }
  __syncthreads();
  const int F = flagL;
  aggL[tid] = 0.f;
  if (tid < 31){                   // softmax((rel+gumbel)/0.5), K=2, max-subtracted
    int e = n*31 + tid;
    float l0 = (inV(rgg,2*e,F)   + inV(gbg,2*e,F))   * 2.f;
    float l1 = (inV(rgg,2*e+1,F) + inV(gbg,2*e+1,F)) * 2.f;
    float m = fmaxf(l0,l1);
    float e0 = __expf(l0-m), e1 = __expf(l1-m);
    float s = 1.f/(e0+e1);
    evL[tid][0] = e0*s; evL[tid][1] = e1*s;
  }
  // evL/aggL first read after the h1all barrier below — safe.

  for (int k=0; k<2; ++k){
    // ---- layer1: h1 = relu(x @ W1[k] + b1[k]) for this thread's 4x8 tile
#pragma unroll
    for (int ri=0; ri<4; ++ri){
      int j = rg + 8*ri;
#pragma unroll
      for (int cc=0; cc<8; ++cc){
        int c = cg*8 + cc;
        float a = inV(b1, k*256 + c, F);
#pragma unroll
        for (int kd=0; kd<8; ++kd)
          a += xj[j][kd] * inV(W1, k*2048 + kd*256 + c, F);
        h1all[j][c] = fmaxf(a, 0.f);
      }
    }
    __syncthreads();               // h1all ready (also publishes evL/aggL on k=0)

    // ---- layer2: h2 = relu(h1 @ W2[k] + b2[k])
    float acc[4][8];
#pragma unroll
    for (int ri=0; ri<4; ++ri)
#pragma unroll
      for (int cc=0; cc<8; ++cc) acc[ri][cc] = inV(b2, k*256 + cg*8 + cc, F);

    for (int jj=0; jj<256; ++jj){
      float wv[8];
#pragma unroll
      for (int cc=0; cc<8; ++cc) wv[cc] = inV(W2, k*65536 + jj*256 + cg*8 + cc, F);
      float hv[4];
#pragma unroll
      for (int ri=0; ri<4; ++ri) hv[ri] = h1all[rg + 8*ri][jj];
#pragma unroll
      for (int ri=0; ri<4; ++ri)
#pragma unroll
        for (int cc=0; cc<8; ++cc) acc[ri][cc] += hv[ri]*wv[cc];
    }

    // ---- edge scale, hooks (k=1), aggregate
#pragma unroll
    for (int ri=0; ri<4; ++ri){
      int j = rg + 8*ri;
      if (j < 31){
        float ev = evL[j][k];
        int hb = (((pstep*8 + tp)*8 + b)*992 + n*31 + j)*256;
#pragma unroll
        for (int cc=0; cc<8; ++cc){
          int c = cg*8 + cc;
          float m = fmaxf(acc[ri][cc], 0.f) * ev;
          if (k == 1) hooks[hb + c] = m;
          atomicAdd(&aggL[c], m);
        }
      }
    }
    __syncthreads();               // h1all reuse next k; aggL complete after k=1
  }

  // ---- output MLP: aug=[last(4), agg(256)] -> Wo1 relu -> Wo2 relu -> Wo3 + residual
  augS[4 + tid] = aggL[tid];
  if (tid < 4) augS[tid] = lastIn[bt*128 + n*4 + tid];
  __syncthreads();
  {
    float a = inV(bo1, tid, F);
    for (int i=0; i<260; ++i) a += augS[i]*inV(Wo1, i*256 + tid, F);
    o1L[tid] = fmaxf(a, 0.f);
  }
  __syncthreads();
  {
    float a = inV(bo2, tid, F);
    for (int i=0; i<256; ++i) a += o1L[i]*inV(Wo2, i*256 + tid, F);
    o2L[tid] = fmaxf(a, 0.f);
  }
  __syncthreads();
  if (tid < 64){
    int d = tid & 3, ch = tid >> 2;        // 16 chunks x 16 elems
    float p = 0.f;
    for (int ii=0; ii<16; ++ii){
      int i = ch*16 + ii;
      p += o2L[i]*inV(Wo3, i*4 + d, F);
    }
#pragma unroll
    for (int s=4; s<64; s<<=1) p += __shfl_xor(p, s);
    if (ch == 0){
      float lv = lastIn[bt*128 + n*4 + d] + p + inV(bo3, d, F);
      lastOut[bt*128 + n*4 + d] = lv;
      int t = tp*4 + pstep;
      if (t < 31) out0[b*3968 + n*124 + t*4 + d] = lv;
    }
  }
}

extern "C" void kernel_launch(void* const* d_in, const int* in_sizes, int n_in,
                              void* d_out, int out_size, void* d_ws, size_t ws_size,
                              hipStream_t stream) {
  const void* inputs    = d_in[0];
  const void* rel_graph = d_in[1];
  const void* W1  = d_in[2];
  const void* b1  = d_in[3];
  const void* W2  = d_in[4];
  const void* b2  = d_in[5];
  const void* Wo1 = d_in[6];
  const void* bo1 = d_in[7];
  const void* Wo2 = d_in[8];
  const void* bo2 = d_in[9];
  const void* Wo3 = d_in[10];
  const void* bo3 = d_in[11];
  const void* gumbel = d_in[14];
  float* out = (float*)d_out;
  char* ws = (char*)d_ws;
  float* L0 = (float*)(ws + WS_LAST0);
  float* L1 = (float*)(ws + WS_LAST1);

  k_prep<<<94, 256, 0, stream>>>(inputs, rel_graph, L0, out);
  for (int p = 0; p < 4; ++p) {
    const float* lin  = (p & 1) ? L1 : L0;
    float*       lout = (p & 1) ? L0 : L1;
    k_step<<<2048, 256, 0, stream>>>(inputs, lin, lout, rel_graph, gumbel,
                                     W1, b1, W2, b2, Wo1, bo1, Wo2, bo2, Wo3, bo3,
                                     out + 47616, out, p);
  }
}